// Round 1
// baseline (3781.766 us; speedup 1.0000x reference)
//
#include <hip/hip_runtime.h>
#include <math.h>

#define KSEQ    256
#define F_SP    32
#define F_FLAT  14
#define D_SP    64
#define D_IN    128
#define D_ST    16
#define DT_RANK 4
#define GD      32
#define DM      64
#define NL      2
#define TCH     16
#define NCH     (KSEQ / TCH)
#define NTHREADS 256

// ---- LDS layout (float offsets) ----
#define SM_XB     0        // 256*64 = 16384   persistent x
#define SM_RAW    16384    // 16*128 = 2048    (alias: ycomb, phase0 staging)
#define SM_XC     18432    // 2048
#define SM_ZB     20480    // 2048
#define SM_DTB    22528    // 2048             (alias: yob)
#define SM_XDBL   24576    // 640 (16*36 used)
#define SM_YPART  25216    // 16*2*128 = 4096  (alias: opart 16*4*64)
#define SM_TAIL   29312    // 3*128 = 384
#define SM_XPW    29696    // 128*36 = 4608
#define SM_DTW    34304    // 4*128 = 512
#define SM_CVW    34816    // 128*4 = 512
#define SM_CVB    35328    // 128
#define SM_DTBIAS 35456    // 128
#define SM_DL     35584    // 128
#define SM_LNG    35712    // 64
#define SM_LNB    35776    // 64
#define SM_MU     35840    // 16
#define SM_RS     35856    // 16
#define SM_HDR    35872    // 392 head scratch
#define SM_TOTAL  36264    // floats -> 145056 bytes (< 160 KiB)

__device__ __forceinline__ float sigf(float x)  { return 1.0f / (1.0f + __expf(-x)); }
__device__ __forceinline__ float siluf(float x) { return x * sigf(x); }
__device__ __forceinline__ float softplusf(float x) {
    return fmaxf(x, 0.0f) + log1pf(__expf(-fabsf(x)));
}

extern "C" __global__ void __launch_bounds__(NTHREADS, 1)
hgsm_fused(const float* __restrict__ x_flat, const float* __restrict__ x_spatial,
           const float* __restrict__ g0w, const float* __restrict__ g0b,
           const float* __restrict__ g0g, const float* __restrict__ g0be,
           const float* __restrict__ g1w, const float* __restrict__ g1b,
           const float* __restrict__ g1g, const float* __restrict__ g1be,
           const float* __restrict__ g2w, const float* __restrict__ g2b,
           const float* __restrict__ g2g, const float* __restrict__ g2be,
           const float* __restrict__ g3w, const float* __restrict__ g3b,
           const float* __restrict__ g3g, const float* __restrict__ g3be,
           const float* __restrict__ sp_w, const float* __restrict__ sp_b,
           const float* __restrict__ in_w, const float* __restrict__ conv_w,
           const float* __restrict__ conv_b, const float* __restrict__ xp_w,
           const float* __restrict__ dt_w, const float* __restrict__ dt_b,
           const float* __restrict__ A_log, const float* __restrict__ Dp,
           const float* __restrict__ out_w, const float* __restrict__ ln_g,
           const float* __restrict__ ln_b, const float* __restrict__ h1_w,
           const float* __restrict__ h1_b, const float* __restrict__ h2_w,
           const float* __restrict__ h2_b, float* __restrict__ out)
{
    extern __shared__ float sm[];
    const int b   = blockIdx.x;
    const int tid = threadIdx.x;

    float* xb    = sm + SM_XB;
    float* raw   = sm + SM_RAW;     // alias: ycomb
    float* xcb   = sm + SM_XC;
    float* zb    = sm + SM_ZB;
    float* dtb   = sm + SM_DTB;     // alias: yob
    float* xdbl  = sm + SM_XDBL;
    float* ypart = sm + SM_YPART;   // alias: opart
    float* tail  = sm + SM_TAIL;
    float* xpw   = sm + SM_XPW;
    float* dtw   = sm + SM_DTW;
    float* cvw   = sm + SM_CVW;
    float* cvb   = sm + SM_CVB;
    float* dtbl  = sm + SM_DTBIAS;
    float* Dl    = sm + SM_DL;
    float* lng   = sm + SM_LNG;
    float* lnb   = sm + SM_LNB;
    float* muA   = sm + SM_MU;
    float* rsA   = sm + SM_RS;
    float* hdr   = sm + SM_HDR;

    // ---------------- Phase 0: x = x_spatial @ sp_w + sp_b ----------------
    {
        float* xsp = raw;  // 8192 floats staging over raw..dtb
        const float4* src = (const float4*)(x_spatial + (size_t)b * KSEQ * F_SP);
        float4* dst = (float4*)xsp;
        for (int i = tid; i < KSEQ * F_SP / 4; i += NTHREADS) dst[i] = src[i];
        __syncthreads();

        const int d  = tid & 63;
        const int tg = tid >> 6;
        float wsp[F_SP];
        #pragma unroll
        for (int f = 0; f < F_SP; ++f) wsp[f] = sp_w[f * D_SP + d];
        const float bias = sp_b[d];
        #pragma unroll 1
        for (int t = tg * 64; t < tg * 64 + 64; ++t) {
            float acc = bias;
            #pragma unroll
            for (int f4 = 0; f4 < F_SP / 4; ++f4) {
                float4 xv = ((const float4*)xsp)[t * (F_SP / 4) + f4];
                acc += xv.x * wsp[f4*4+0] + xv.y * wsp[f4*4+1]
                     + xv.z * wsp[f4*4+2] + xv.w * wsp[f4*4+3];
            }
            xb[t * D_SP + d] = acc;
        }
        __syncthreads();
    }

    // scan mapping: thread owns (d_sc, 8 states of half sh)
    const int d_sc = tid & 127;
    const int sh   = tid >> 7;
    // out_proj mapping
    const int jo = tid & 63;
    const int dg = tid >> 6;

    // ---------------- Mamba layers ----------------
    #pragma unroll 1
    for (int l = 0; l < NL; ++l) {
        // stage layer weights into LDS
        for (int i = tid; i < D_IN * 36; i += NTHREADS) xpw[i] = xp_w[(size_t)l * D_IN * 36 + i];
        for (int i = tid; i < DT_RANK * D_IN; i += NTHREADS) dtw[i] = dt_w[(size_t)l * DT_RANK * D_IN + i];
        for (int i = tid; i < D_IN * 4; i += NTHREADS) cvw[i] = conv_w[(size_t)l * D_IN * 4 + i];
        if (tid < D_IN) {
            cvb[tid]  = conv_b[l * D_IN + tid];
            dtbl[tid] = dt_b[l * D_IN + tid];
            Dl[tid]   = Dp[l * D_IN + tid];
        }
        if (tid < D_SP) {
            lng[tid] = ln_g[l * D_SP + tid];
            lnb[tid] = ln_b[l * D_SP + tid];
        }
        for (int i = tid; i < 3 * D_IN; i += NTHREADS) tail[i] = 0.0f;

        // per-thread register weights
        float win[D_SP];
        #pragma unroll
        for (int i = 0; i < D_SP; ++i)
            win[i] = in_w[(size_t)l * D_SP * 256 + i * 256 + tid];
        float wout[32];
        #pragma unroll
        for (int m = 0; m < 32; ++m)
            wout[m] = out_w[(size_t)l * D_IN * D_SP + (dg * 32 + m) * D_SP + jo];
        float aA[8];
        #pragma unroll
        for (int s = 0; s < 8; ++s)
            aA[s] = -__expf(A_log[(size_t)l * D_IN * D_ST + d_sc * D_ST + sh * 8 + s]);
        float hst[8];
        #pragma unroll
        for (int s = 0; s < 8; ++s) hst[s] = 0.0f;

        __syncthreads();

        #pragma unroll 1
        for (int c = 0; c < NCH; ++c) {
            const int t0 = c * TCH;

            // ---- in_proj: xz[t][tid] = x[t] . in_w[:,tid] ----
            float acc[TCH];
            #pragma unroll
            for (int t = 0; t < TCH; ++t) acc[t] = 0.0f;
            #pragma unroll
            for (int i4 = 0; i4 < D_SP / 4; ++i4) {
                const float w0 = win[i4*4+0], w1 = win[i4*4+1];
                const float w2 = win[i4*4+2], w3 = win[i4*4+3];
                #pragma unroll
                for (int t = 0; t < TCH; ++t) {
                    float4 xv = ((const float4*)xb)[(t0 + t) * (D_SP / 4) + i4];
                    acc[t] += xv.x * w0 + xv.y * w1 + xv.z * w2 + xv.w * w3;
                }
            }
            if (tid < D_IN) {
                #pragma unroll
                for (int t = 0; t < TCH; ++t) raw[t * D_IN + tid] = acc[t];
            } else {
                #pragma unroll
                for (int t = 0; t < TCH; ++t) zb[t * D_IN + (tid - D_IN)] = acc[t];
            }
            __syncthreads();  // B1

            // ---- causal depthwise conv (k=4) + bias + silu ----
            for (int idx = tid; idx < TCH * D_IN; idx += NTHREADS) {
                const int t = idx >> 7, d = idx & 127;
                float s = cvb[d];
                #pragma unroll
                for (int k = 0; k < 4; ++k) {
                    const int tt = t - 3 + k;
                    const float v = (tt >= 0) ? raw[tt * D_IN + d] : tail[(tt + 3) * D_IN + d];
                    s += cvw[d * 4 + k] * v;
                }
                xcb[idx] = siluf(s);
            }
            __syncthreads();  // B2

            // ---- save tail (raw rows 13..15) + xp projection ----
            for (int idx = tid; idx < 3 * D_IN; idx += NTHREADS)
                tail[idx] = raw[(TCH - 3) * D_IN + idx];
            for (int idx = tid; idx < TCH * 36; idx += NTHREADS) {
                const int t = idx / 36, j = idx - t * 36;
                float s = 0.0f;
                #pragma unroll
                for (int d4 = 0; d4 < D_IN / 4; ++d4) {
                    float4 xv = ((const float4*)xcb)[t * (D_IN / 4) + d4];
                    s += xv.x * xpw[(d4*4+0)*36 + j] + xv.y * xpw[(d4*4+1)*36 + j]
                       + xv.z * xpw[(d4*4+2)*36 + j] + xv.w * xpw[(d4*4+3)*36 + j];
                }
                xdbl[t * 36 + j] = s;
            }
            __syncthreads();  // B3

            // ---- dt = softplus(xdbl[:, :4] @ dt_w + dt_b) ----
            for (int idx = tid; idx < TCH * D_IN; idx += NTHREADS) {
                const int t = idx >> 7, dch = idx & 127;
                float v = dtbl[dch];
                #pragma unroll
                for (int r = 0; r < DT_RANK; ++r)
                    v += xdbl[t * 36 + r] * dtw[r * D_IN + dch];
                dtb[idx] = softplusf(v);
            }
            __syncthreads();  // B4

            // ---- selective scan over the chunk ----
            #pragma unroll 1
            for (int t = 0; t < TCH; ++t) {
                const float dtv = dtb[t * D_IN + d_sc];
                const float xv  = xcb[t * D_IN + d_sc];
                const float dx  = dtv * xv;
                float yp = 0.0f;
                #pragma unroll
                for (int s = 0; s < 8; ++s) {
                    const float Bv = xdbl[t * 36 + DT_RANK + sh * 8 + s];
                    const float Cv = xdbl[t * 36 + DT_RANK + D_ST + sh * 8 + s];
                    const float dA = __expf(dtv * aA[s]);
                    hst[s] = dA * hst[s] + dx * Bv;
                    yp += hst[s] * Cv;
                }
                ypart[(t * 2 + sh) * D_IN + d_sc] = yp;
            }
            __syncthreads();  // B5

            // ---- ycomb = (y_scan + xc*D) * silu(z)   (into raw) ----
            float* ycb = raw;
            for (int idx = tid; idx < TCH * D_IN; idx += NTHREADS) {
                const int t = idx >> 7, d = idx & 127;
                const float v = ypart[(t * 2) * D_IN + d] + ypart[(t * 2 + 1) * D_IN + d]
                              + xcb[idx] * Dl[d];
                ycb[idx] = v * siluf(zb[idx]);
            }
            __syncthreads();  // B6

            // ---- out_proj partials: opart[t][dg][jo] ----
            float* opart = ypart;
            #pragma unroll 1
            for (int t = 0; t < TCH; ++t) {
                float s = 0.0f;
                #pragma unroll
                for (int m = 0; m < 32; ++m)
                    s += ycb[t * D_IN + dg * 32 + m] * wout[m];
                opart[(t * 4 + dg) * 64 + jo] = s;
            }
            __syncthreads();  // B7

            // ---- combine partials -> yob (alias dtb) ----
            float* yob = dtb;
            for (int idx = tid; idx < TCH * D_SP; idx += NTHREADS) {
                const int t = idx >> 6, j = idx & 63;
                yob[idx] = opart[(t * 4 + 0) * 64 + j] + opart[(t * 4 + 1) * 64 + j]
                         + opart[(t * 4 + 2) * 64 + j] + opart[(t * 4 + 3) * 64 + j];
            }
            __syncthreads();  // B8

            // ---- layernorm stats per token ----
            if (tid < TCH) {
                const int t = tid;
                float mu = 0.0f;
                #pragma unroll
                for (int j = 0; j < D_SP; ++j) mu += yob[t * 64 + j];
                mu *= (1.0f / D_SP);
                float var = 0.0f;
                #pragma unroll
                for (int j = 0; j < D_SP; ++j) {
                    const float dd = yob[t * 64 + j] - mu;
                    var += dd * dd;
                }
                var *= (1.0f / D_SP);
                muA[t] = mu;
                rsA[t] = rsqrtf(var + 1e-5f);
            }
            __syncthreads();  // B9

            // ---- apply LN + residual into xb ----
            for (int idx = tid; idx < TCH * D_SP; idx += NTHREADS) {
                const int t = idx >> 6, j = idx & 63;
                const float v = (yob[idx] - muA[t]) * rsA[t] * lng[j] + lnb[j];
                xb[(t0 + t) * D_SP + j] += v;
            }
            __syncthreads();  // B10 (end of chunk)
        }
    }

    // ---------------- Head ----------------
    float* comb  = hdr;        // 192
    float* gh    = hdr + 192;  // 128
    float* hb1   = hdr + 320;  // 64
    float* gstat = hdr + 384;  // 8

    if (tid < D_SP) {
        float s = 0.0f;
        #pragma unroll 4
        for (int t = 0; t < KSEQ; ++t) s += xb[t * D_SP + tid];
        comb[4 * GD + tid] = s * (1.0f / KSEQ);
    } else if (tid < 192) {
        const int g = (tid - 64) >> 5, c = (tid - 64) & 31;
        const float* gw; const float* gb; int dd, so;
        if      (g == 0) { gw = g0w; gb = g0b; dd = 4; so = 0;  }
        else if (g == 1) { gw = g1w; gb = g1b; dd = 3; so = 4;  }
        else if (g == 2) { gw = g2w; gb = g2b; dd = 4; so = 7;  }
        else             { gw = g3w; gb = g3b; dd = 3; so = 11; }
        float acc = gb[c];
        for (int f = 0; f < dd; ++f)
            acc += x_flat[(size_t)b * F_FLAT + so + f] * gw[f * GD + c];
        gh[tid - 64] = fmaxf(acc, 0.0f);
    }
    __syncthreads();

    if (tid < 4) {
        float mu = 0.0f;
        #pragma unroll
        for (int c = 0; c < GD; ++c) mu += gh[tid * GD + c];
        mu *= (1.0f / GD);
        float var = 0.0f;
        #pragma unroll
        for (int c = 0; c < GD; ++c) {
            const float dd = gh[tid * GD + c] - mu;
            var += dd * dd;
        }
        var *= (1.0f / GD);
        gstat[tid] = mu;
        gstat[4 + tid] = rsqrtf(var + 1e-5f);
    }
    __syncthreads();

    if (tid < 128) {
        const int g = tid >> 5, c = tid & 31;
        const float* gg; const float* gbe;
        if      (g == 0) { gg = g0g; gbe = g0be; }
        else if (g == 1) { gg = g1g; gbe = g1be; }
        else if (g == 2) { gg = g2g; gbe = g2be; }
        else             { gg = g3g; gbe = g3be; }
        comb[tid] = (gh[tid] - gstat[g]) * gstat[4 + g] * gg[c] + gbe[c];
    }
    __syncthreads();

    if (tid < DM) {
        float acc = h1_b[tid];
        #pragma unroll 4
        for (int k = 0; k < 4 * GD + D_SP; ++k) acc += comb[k] * h1_w[k * DM + tid];
        hb1[tid] = fmaxf(acc, 0.0f);
    }
    __syncthreads();

    if (tid == 0) {
        float acc = h2_b[0];
        #pragma unroll
        for (int j = 0; j < DM; ++j) acc += hb1[j] * h2_w[j];
        out[b] = 1.0f / (1.0f + __expf(-acc));
    }
}

extern "C" void kernel_launch(void* const* d_in, const int* in_sizes, int n_in,
                              void* d_out, int out_size, void* d_ws, size_t ws_size,
                              hipStream_t stream) {
    (void)n_in; (void)d_ws; (void)ws_size;
    const float* x_flat    = (const float*)d_in[0];
    const float* x_spatial = (const float*)d_in[1];
    const float* g0w = (const float*)d_in[2];
    const float* g0b = (const float*)d_in[3];
    const float* g0g = (const float*)d_in[4];
    const float* g0be = (const float*)d_in[5];
    const float* g1w = (const float*)d_in[6];
    const float* g1b = (const float*)d_in[7];
    const float* g1g = (const float*)d_in[8];
    const float* g1be = (const float*)d_in[9];
    const float* g2w = (const float*)d_in[10];
    const float* g2b = (const float*)d_in[11];
    const float* g2g = (const float*)d_in[12];
    const float* g2be = (const float*)d_in[13];
    const float* g3w = (const float*)d_in[14];
    const float* g3b = (const float*)d_in[15];
    const float* g3g = (const float*)d_in[16];
    const float* g3be = (const float*)d_in[17];
    const float* sp_w = (const float*)d_in[18];
    const float* sp_b = (const float*)d_in[19];
    const float* in_w = (const float*)d_in[20];
    const float* conv_w = (const float*)d_in[21];
    const float* conv_b = (const float*)d_in[22];
    const float* xp_w = (const float*)d_in[23];
    const float* dt_w = (const float*)d_in[24];
    const float* dt_b = (const float*)d_in[25];
    const float* A_log = (const float*)d_in[26];
    const float* Dp = (const float*)d_in[27];
    const float* out_w = (const float*)d_in[28];
    const float* ln_g = (const float*)d_in[29];
    const float* ln_b = (const float*)d_in[30];
    const float* h1_w = (const float*)d_in[31];
    const float* h1_b = (const float*)d_in[32];
    const float* h2_w = (const float*)d_in[33];
    const float* h2_b = (const float*)d_in[34];
    float* out = (float*)d_out;

    const int B = in_sizes[0] / F_FLAT;
    const size_t shmem = (size_t)SM_TOTAL * sizeof(float);
    (void)hipFuncSetAttribute((const void*)hgsm_fused,
                              hipFuncAttributeMaxDynamicSharedMemorySize, (int)shmem);

    hipLaunchKernelGGL(hgsm_fused, dim3(B), dim3(NTHREADS), shmem, stream,
                       x_flat, x_spatial,
                       g0w, g0b, g0g, g0be, g1w, g1b, g1g, g1be,
                       g2w, g2b, g2g, g2be, g3w, g3b, g3g, g3be,
                       sp_w, sp_b, in_w, conv_w, conv_b, xp_w, dt_w, dt_b,
                       A_log, Dp, out_w, ln_g, ln_b, h1_w, h1_b, h2_w, h2_b,
                       out);
}

// Round 2
// 2980.133 us; speedup vs baseline: 1.2690x; 1.2690x over previous
//
#include <hip/hip_runtime.h>
#include <math.h>

#define KSEQ    256
#define F_SP    32
#define F_FLAT  14
#define D_SP    64
#define D_IN    128
#define D_ST    16
#define DT_RANK 4
#define GD      32
#define DM      64
#define NL      2
#define TCH     16
#define NCH     (KSEQ / TCH)
#define NTHREADS 512

// ---- LDS layout (float offsets) ----
#define SM_XB     0        // 256*64 = 16384   persistent x
#define SM_RAW    16384    // 16*128 = 2048    (alias: ycomb, phase0 staging spans RAW..DTB)
#define SM_XC     18432    // 2048
#define SM_ZB     20480    // 2048
#define SM_DTB    22528    // 2048
#define SM_XDBL   24576    // 640 (16*36 used)
#define SM_YBOP   25216    // 4096: yb (16*128) then opart (16*4*64)
#define SM_TAIL   29312    // 3*128 = 384
#define SM_XPW    29696    // 128*36 = 4608
#define SM_DTW    34304    // 4*128 = 512
#define SM_CVW    34816    // 4*128 = 512  (transposed: [k][d])
#define SM_CVB    35328    // 128
#define SM_DTBIAS 35456    // 128
#define SM_DL     35584    // 128
#define SM_LNG    35712    // 64
#define SM_LNB    35776    // 64
#define SM_HDR    35840    // 960 head scratch (psum 512 + comb 192 + gh 128 + hb1 64 + gstat 8)
#define SM_TOTAL  36800    // floats -> 147200 bytes (< 160 KiB)

__device__ __forceinline__ float sigf(float x)  { return 1.0f / (1.0f + __expf(-x)); }
__device__ __forceinline__ float siluf(float x) { return x * sigf(x); }
__device__ __forceinline__ float softplusf(float x) {
    return fmaxf(x, 0.0f) + log1pf(__expf(-fabsf(x)));
}

extern "C" __global__ void __launch_bounds__(NTHREADS, 1)
hgsm_fused(const float* __restrict__ x_flat, const float* __restrict__ x_spatial,
           const float* __restrict__ g0w, const float* __restrict__ g0b,
           const float* __restrict__ g0g, const float* __restrict__ g0be,
           const float* __restrict__ g1w, const float* __restrict__ g1b,
           const float* __restrict__ g1g, const float* __restrict__ g1be,
           const float* __restrict__ g2w, const float* __restrict__ g2b,
           const float* __restrict__ g2g, const float* __restrict__ g2be,
           const float* __restrict__ g3w, const float* __restrict__ g3b,
           const float* __restrict__ g3g, const float* __restrict__ g3be,
           const float* __restrict__ sp_w, const float* __restrict__ sp_b,
           const float* __restrict__ in_w, const float* __restrict__ conv_w,
           const float* __restrict__ conv_b, const float* __restrict__ xp_w,
           const float* __restrict__ dt_w, const float* __restrict__ dt_b,
           const float* __restrict__ A_log, const float* __restrict__ Dp,
           const float* __restrict__ out_w, const float* __restrict__ ln_g,
           const float* __restrict__ ln_b, const float* __restrict__ h1_w,
           const float* __restrict__ h1_b, const float* __restrict__ h2_w,
           const float* __restrict__ h2_b, float* __restrict__ out)
{
    extern __shared__ float sm[];
    const int b   = blockIdx.x;
    const int tid = threadIdx.x;

    float* xb    = sm + SM_XB;
    float* raw   = sm + SM_RAW;     // alias: ycomb
    float* xcb   = sm + SM_XC;
    float* zb    = sm + SM_ZB;
    float* dtb   = sm + SM_DTB;
    float* xdbl  = sm + SM_XDBL;
    float* ybop  = sm + SM_YBOP;    // yb during scan, opart during out_proj
    float* tail  = sm + SM_TAIL;
    float* xpw   = sm + SM_XPW;
    float* dtw   = sm + SM_DTW;
    float* cvwT  = sm + SM_CVW;
    float* cvb   = sm + SM_CVB;
    float* dtbl  = sm + SM_DTBIAS;
    float* Dl    = sm + SM_DL;
    float* lng   = sm + SM_LNG;
    float* lnb   = sm + SM_LNB;
    float* hdr   = sm + SM_HDR;

    // ---------------- Phase 0: x = x_spatial @ sp_w + sp_b ----------------
    {
        float* xsp = raw;  // 8192 floats staging over raw..dtb
        const float4* src = (const float4*)(x_spatial + (size_t)b * KSEQ * F_SP);
        float4* dst = (float4*)xsp;
        for (int i = tid; i < KSEQ * F_SP / 4; i += NTHREADS) dst[i] = src[i];
        __syncthreads();

        const int d  = tid & 63;
        const int tg = tid >> 6;   // 0..7, 32 tokens each
        float wsp[F_SP];
        #pragma unroll
        for (int f = 0; f < F_SP; ++f) wsp[f] = sp_w[f * D_SP + d];
        const float bias = sp_b[d];
        #pragma unroll 1
        for (int t = tg * 32; t < tg * 32 + 32; ++t) {
            float acc = bias;
            #pragma unroll
            for (int f4 = 0; f4 < F_SP / 4; ++f4) {
                float4 xv = ((const float4*)xsp)[t * (F_SP / 4) + f4];
                acc += xv.x * wsp[f4*4+0] + xv.y * wsp[f4*4+1]
                     + xv.z * wsp[f4*4+2] + xv.w * wsp[f4*4+3];
            }
            xb[t * D_SP + d] = acc;
        }
        __syncthreads();
    }

    // thread mappings
    const int col  = tid & 255;        // in_proj column
    const int th   = tid >> 8;         // token half (0/1)
    const int d_sc = tid >> 2;         // scan channel (adjacent lanes share channel)
    const int shq  = tid & 3;          // scan state shard (4 states each)
    const int jo   = tid & 63;         // out_proj output
    const int dgq  = (tid >> 6) & 3;   // out_proj channel group
    const int t_ln = tid >> 5;         // LN token
    const int j_ln = tid & 31;         // LN column pair (j, j+32)

    // ---------------- Mamba layers ----------------
    #pragma unroll 1
    for (int l = 0; l < NL; ++l) {
        // stage layer weights into LDS
        for (int i = tid; i < D_IN * 36; i += NTHREADS) xpw[i] = xp_w[(size_t)l * D_IN * 36 + i];
        if (tid < DT_RANK * D_IN) dtw[tid] = dt_w[(size_t)l * DT_RANK * D_IN + tid];
        if (tid < D_IN * 4) {
            const int k = tid >> 7, d = tid & 127;   // transposed [k][d]
            cvwT[tid] = conv_w[(size_t)l * D_IN * 4 + d * 4 + k];
        }
        if (tid < D_IN) {
            cvb[tid]  = conv_b[l * D_IN + tid];
            dtbl[tid] = dt_b[l * D_IN + tid];
            Dl[tid]   = Dp[l * D_IN + tid];
        }
        if (tid < D_SP) {
            lng[tid] = ln_g[l * D_SP + tid];
            lnb[tid] = ln_b[l * D_SP + tid];
        }
        if (tid < 3 * D_IN) tail[tid] = 0.0f;

        // per-thread register weights
        float win[D_SP];
        #pragma unroll
        for (int i = 0; i < D_SP; ++i)
            win[i] = in_w[(size_t)l * D_SP * 256 + i * 256 + col];
        float wout[32];
        #pragma unroll
        for (int m = 0; m < 32; ++m)
            wout[m] = out_w[(size_t)l * D_IN * D_SP + (dgq * 32 + m) * D_SP + jo];
        float aA[4];
        #pragma unroll
        for (int s = 0; s < 4; ++s)
            aA[s] = -__expf(A_log[(size_t)l * D_IN * D_ST + d_sc * D_ST + shq * 4 + s]);
        float hst[4];
        #pragma unroll
        for (int s = 0; s < 4; ++s) hst[s] = 0.0f;

        __syncthreads();

        #pragma unroll 1
        for (int c = 0; c < NCH; ++c) {
            const int t0 = c * TCH;

            // ---- in_proj: 8 tokens per thread for column `col` ----
            float acc[8];
            #pragma unroll
            for (int t = 0; t < 8; ++t) acc[t] = 0.0f;
            #pragma unroll
            for (int i4 = 0; i4 < D_SP / 4; ++i4) {
                const float w0 = win[i4*4+0], w1 = win[i4*4+1];
                const float w2 = win[i4*4+2], w3 = win[i4*4+3];
                #pragma unroll
                for (int t = 0; t < 8; ++t) {
                    float4 xv = ((const float4*)xb)[(t0 + th * 8 + t) * (D_SP / 4) + i4];
                    acc[t] += xv.x * w0 + xv.y * w1 + xv.z * w2 + xv.w * w3;
                }
            }
            if (col < D_IN) {
                #pragma unroll
                for (int t = 0; t < 8; ++t) raw[(th * 8 + t) * D_IN + col] = acc[t];
            } else {
                #pragma unroll
                for (int t = 0; t < 8; ++t) zb[(th * 8 + t) * D_IN + (col - D_IN)] = acc[t];
            }
            __syncthreads();  // B1

            // ---- causal depthwise conv (k=4) + bias + silu ----
            for (int idx = tid; idx < TCH * D_IN; idx += NTHREADS) {
                const int t = idx >> 7, d = idx & 127;
                float s = cvb[d];
                #pragma unroll
                for (int k = 0; k < 4; ++k) {
                    const int tt = t - 3 + k;
                    const float v = (tt >= 0) ? raw[tt * D_IN + d] : tail[(tt + 3) * D_IN + d];
                    s += cvwT[k * D_IN + d] * v;
                }
                xcb[idx] = siluf(s);
            }
            __syncthreads();  // B2

            // ---- save tail (raw rows 13..15) + xp projection ----
            if (tid < 3 * D_IN) tail[tid] = raw[(TCH - 3) * D_IN + tid];
            for (int idx = tid; idx < TCH * 36; idx += NTHREADS) {
                const int t = idx / 36, j = idx - t * 36;
                float s = 0.0f;
                #pragma unroll
                for (int d4 = 0; d4 < D_IN / 4; ++d4) {
                    float4 xv = ((const float4*)xcb)[t * (D_IN / 4) + d4];
                    s += xv.x * xpw[(d4*4+0)*36 + j] + xv.y * xpw[(d4*4+1)*36 + j]
                       + xv.z * xpw[(d4*4+2)*36 + j] + xv.w * xpw[(d4*4+3)*36 + j];
                }
                xdbl[t * 36 + j] = s;
            }
            __syncthreads();  // B3

            // ---- dt = softplus(xdbl[:, :4] @ dt_w + dt_b) ----
            for (int idx = tid; idx < TCH * D_IN; idx += NTHREADS) {
                const int t = idx >> 7, dch = idx & 127;
                float v = dtbl[dch];
                #pragma unroll
                for (int r = 0; r < DT_RANK; ++r)
                    v += xdbl[t * 36 + r] * dtw[r * D_IN + dch];
                dtb[idx] = softplusf(v);
            }
            __syncthreads();  // B4

            // ---- selective scan over the chunk (4 states/thread, shfl reduce) ----
            float* yb = ybop;
            #pragma unroll
            for (int t = 0; t < TCH; ++t) {
                const float dtv = dtb[t * D_IN + d_sc];
                const float xv  = xcb[t * D_IN + d_sc];
                const float dx  = dtv * xv;
                float yp = 0.0f;
                #pragma unroll
                for (int s = 0; s < 4; ++s) {
                    const float Bv = xdbl[t * 36 + DT_RANK + shq * 4 + s];
                    const float Cv = xdbl[t * 36 + DT_RANK + D_ST + shq * 4 + s];
                    const float dA = __expf(dtv * aA[s]);
                    hst[s] = dA * hst[s] + dx * Bv;
                    yp += hst[s] * Cv;
                }
                yp += __shfl_xor(yp, 1, 64);
                yp += __shfl_xor(yp, 2, 64);
                if (shq == 0) yb[t * D_IN + d_sc] = yp;
            }
            __syncthreads();  // B5

            // ---- ycomb = (y_scan + xc*D) * silu(z)   (into raw) ----
            float* ycb = raw;
            for (int idx = tid; idx < TCH * D_IN; idx += NTHREADS) {
                const int d = idx & 127;
                const float v = yb[idx] + xcb[idx] * Dl[d];
                ycb[idx] = v * siluf(zb[idx]);
            }
            __syncthreads();  // B6

            // ---- out_proj partials: opart[t][dgq][jo], 8 tokens per thread ----
            float* opart = ybop;
            #pragma unroll 1
            for (int tl = 0; tl < 8; ++tl) {
                const int t = th * 8 + tl;
                float s = 0.0f;
                #pragma unroll
                for (int m = 0; m < 32; ++m)
                    s += ycb[t * D_IN + dgq * 32 + m] * wout[m];
                opart[(t * 4 + dgq) * 64 + jo] = s;
            }
            __syncthreads();  // B7

            // ---- combine partials + LN (butterfly stats) + residual ----
            {
                float s1 = 0.0f, s2 = 0.0f;
                #pragma unroll
                for (int g = 0; g < 4; ++g) {
                    s1 += opart[(t_ln * 4 + g) * 64 + j_ln];
                    s2 += opart[(t_ln * 4 + g) * 64 + j_ln + 32];
                }
                float sum = s1 + s2;
                float ssq = s1 * s1 + s2 * s2;
                #pragma unroll
                for (int m = 1; m <= 16; m <<= 1) {
                    sum += __shfl_xor(sum, m, 64);
                    ssq += __shfl_xor(ssq, m, 64);
                }
                const float mu = sum * (1.0f / D_SP);
                const float var = ssq * (1.0f / D_SP) - mu * mu;
                const float rs = rsqrtf(var + 1e-5f);
                xb[(t0 + t_ln) * D_SP + j_ln]      += (s1 - mu) * rs * lng[j_ln] + lnb[j_ln];
                xb[(t0 + t_ln) * D_SP + j_ln + 32] += (s2 - mu) * rs * lng[j_ln + 32] + lnb[j_ln + 32];
            }
            __syncthreads();  // B8 (end of chunk)
        }
    }

    // ---------------- Head ----------------
    float* psum  = hdr;        // 8*64 = 512
    float* comb  = hdr + 512;  // 192
    float* gh    = hdr + 704;  // 128
    float* hb1   = hdr + 832;  // 64
    float* gstat = hdr + 896;  // 8

    // P1: mean partials (all threads) + group MLPs (threads 64..191)
    {
        const int d = tid & 63, grp = tid >> 6;  // 8 groups x 32 tokens
        float s = 0.0f;
        #pragma unroll 4
        for (int t = grp * 32; t < grp * 32 + 32; ++t) s += xb[t * D_SP + d];
        psum[grp * 64 + d] = s;
    }
    if (tid >= 64 && tid < 192) {
        const int g = (tid - 64) >> 5, cc = (tid - 64) & 31;
        const float* gw; const float* gb; int dd, so;
        if      (g == 0) { gw = g0w; gb = g0b; dd = 4; so = 0;  }
        else if (g == 1) { gw = g1w; gb = g1b; dd = 3; so = 4;  }
        else if (g == 2) { gw = g2w; gb = g2b; dd = 4; so = 7;  }
        else             { gw = g3w; gb = g3b; dd = 3; so = 11; }
        float acc = gb[cc];
        for (int f = 0; f < dd; ++f)
            acc += x_flat[(size_t)b * F_FLAT + so + f] * gw[f * GD + cc];
        gh[tid - 64] = fmaxf(acc, 0.0f);
    }
    __syncthreads();

    // P2: combine mean; group LN stats
    if (tid < D_SP) {
        float s = 0.0f;
        #pragma unroll
        for (int g = 0; g < 8; ++g) s += psum[g * 64 + tid];
        comb[4 * GD + tid] = s * (1.0f / KSEQ);
    } else if (tid >= 512 - 4) {
        const int g = tid - (512 - 4);
        float mu = 0.0f;
        #pragma unroll
        for (int cc = 0; cc < GD; ++cc) mu += gh[g * GD + cc];
        mu *= (1.0f / GD);
        float var = 0.0f;
        #pragma unroll
        for (int cc = 0; cc < GD; ++cc) {
            const float dd = gh[g * GD + cc] - mu;
            var += dd * dd;
        }
        var *= (1.0f / GD);
        gstat[g] = mu;
        gstat[4 + g] = rsqrtf(var + 1e-5f);
    }
    __syncthreads();

    // P3: group LN apply
    if (tid < 128) {
        const int g = tid >> 5, cc = tid & 31;
        const float* gg; const float* gbe;
        if      (g == 0) { gg = g0g; gbe = g0be; }
        else if (g == 1) { gg = g1g; gbe = g1be; }
        else if (g == 2) { gg = g2g; gbe = g2be; }
        else             { gg = g3g; gbe = g3be; }
        comb[tid] = (gh[tid] - gstat[g]) * gstat[4 + g] * gg[cc] + gbe[cc];
    }
    __syncthreads();

    // P4: h1
    if (tid < DM) {
        float acc = h1_b[tid];
        #pragma unroll 4
        for (int k = 0; k < 4 * GD + D_SP; ++k) acc += comb[k] * h1_w[k * DM + tid];
        hb1[tid] = fmaxf(acc, 0.0f);
    }
    __syncthreads();

    // P5: h2 + sigmoid
    if (tid == 0) {
        float acc = h2_b[0];
        #pragma unroll
        for (int j = 0; j < DM; ++j) acc += hb1[j] * h2_w[j];
        out[b] = 1.0f / (1.0f + __expf(-acc));
    }
}

extern "C" void kernel_launch(void* const* d_in, const int* in_sizes, int n_in,
                              void* d_out, int out_size, void* d_ws, size_t ws_size,
                              hipStream_t stream) {
    (void)n_in; (void)d_ws; (void)ws_size; (void)out_size;
    const float* x_flat    = (const float*)d_in[0];
    const float* x_spatial = (const float*)d_in[1];
    const float* g0w = (const float*)d_in[2];
    const float* g0b = (const float*)d_in[3];
    const float* g0g = (const float*)d_in[4];
    const float* g0be = (const float*)d_in[5];
    const float* g1w = (const float*)d_in[6];
    const float* g1b = (const float*)d_in[7];
    const float* g1g = (const float*)d_in[8];
    const float* g1be = (const float*)d_in[9];
    const float* g2w = (const float*)d_in[10];
    const float* g2b = (const float*)d_in[11];
    const float* g2g = (const float*)d_in[12];
    const float* g2be = (const float*)d_in[13];
    const float* g3w = (const float*)d_in[14];
    const float* g3b = (const float*)d_in[15];
    const float* g3g = (const float*)d_in[16];
    const float* g3be = (const float*)d_in[17];
    const float* sp_w = (const float*)d_in[18];
    const float* sp_b = (const float*)d_in[19];
    const float* in_w = (const float*)d_in[20];
    const float* conv_w = (const float*)d_in[21];
    const float* conv_b = (const float*)d_in[22];
    const float* xp_w = (const float*)d_in[23];
    const float* dt_w = (const float*)d_in[24];
    const float* dt_b = (const float*)d_in[25];
    const float* A_log = (const float*)d_in[26];
    const float* Dp = (const float*)d_in[27];
    const float* out_w = (const float*)d_in[28];
    const float* ln_g = (const float*)d_in[29];
    const float* ln_b = (const float*)d_in[30];
    const float* h1_w = (const float*)d_in[31];
    const float* h1_b = (const float*)d_in[32];
    const float* h2_w = (const float*)d_in[33];
    const float* h2_b = (const float*)d_in[34];
    float* out = (float*)d_out;

    const int B = in_sizes[0] / F_FLAT;
    const size_t shmem = (size_t)SM_TOTAL * sizeof(float);
    (void)hipFuncSetAttribute((const void*)hgsm_fused,
                              hipFuncAttributeMaxDynamicSharedMemorySize, (int)shmem);

    hipLaunchKernelGGL(hgsm_fused, dim3(B), dim3(NTHREADS), shmem, stream,
                       x_flat, x_spatial,
                       g0w, g0b, g0g, g0be, g1w, g1b, g1g, g1be,
                       g2w, g2b, g2g, g2be, g3w, g3b, g3g, g3be,
                       sp_w, sp_b, in_w, conv_w, conv_b, xp_w, dt_w, dt_b,
                       A_log, Dp, out_w, ln_g, ln_b, h1_w, h1_b, h2_w, h2_b,
                       out);
}

// Round 3
// 1057.734 us; speedup vs baseline: 3.5753x; 2.8175x over previous
//
#include <hip/hip_runtime.h>
#include <math.h>

#define KSEQ    256
#define F_SP    32
#define F_FLAT  14
#define D_SP    64
#define D_IN    128
#define D_ST    16
#define DT_RANK 4
#define GD      32
#define DM      64
#define NL      2
#define TCH     16
#define NCH     (KSEQ / TCH)
#define NTHREADS 512

// ---- LDS layout (BYTE offsets, all 16B-aligned) ----
// bf16 buffers padded: xb stride 72 (bank-decorrelated), activation tiles stride 136
#define OFF_XB    0        // ushort 256*72      = 36864 B   persistent x (bf16)
#define OFF_RAW   36864    // ushort 16*136      = 4352 B    xz pre-conv (bf16)
#define OFF_ZB    41216    // ushort 16*136      = 4352 B    z gate (bf16)
#define OFF_XCB   45568    // ushort 16*136      = 4352 B    conv+silu out (bf16)
#define OFF_YCB   49920    // ushort 16*136      = 4352 B    gated scan out (bf16)
#define OFF_DTB   54272    // float  16*128      = 8192 B    dt (fp32)   [head scratch aliases here]
#define OFF_XDBL  62464    // float  16*48       = 3072 B    xp out (fp32, stride 48)
#define OFF_YOB   65536    // float  16*65       = 4160 B    out_proj out (fp32, stride 65)
#define OFF_TAIL  69696    // ushort 3*128       = 768 B     conv tail (bf16)
#define OFF_DTW   70464    // float  4*128       = 2048 B
#define OFF_CVWT  72512    // float  4*128       = 2048 B    conv_w transposed [k][d]
#define OFF_CVB   74560    // float  128         = 512 B
#define OFF_DTBL  75072    // float  128         = 512 B
#define OFF_DL    75584    // float  128         = 512 B
#define OFF_LNG   76096    // float  64          = 256 B
#define OFF_LNB   76352    // float  64          = 256 B
#define SM_BYTES  76608    // 74.8 KiB -> 2 blocks/CU (160 KiB budget)
// phase0 staging (32 KB fp32) aliases OFF_RAW..OFF_YOB (32832 B available)

typedef __attribute__((ext_vector_type(8))) short bf16x8;
typedef __attribute__((ext_vector_type(4))) float f32x4;

__device__ __forceinline__ unsigned short f2bf(float f) {
    union { float f; unsigned int u; } v; v.f = f;
    unsigned int r = v.u + 0x7FFFu + ((v.u >> 16) & 1u);   // RNE
    return (unsigned short)(r >> 16);
}
__device__ __forceinline__ float bf2f(unsigned short h) {
    union { unsigned int u; float f; } v; v.u = ((unsigned int)h) << 16; return v.f;
}
__device__ __forceinline__ float sigf(float x)  { return 1.0f / (1.0f + __expf(-x)); }
__device__ __forceinline__ float siluf(float x) { return x * sigf(x); }
__device__ __forceinline__ float softplusf(float x) {
    return fmaxf(x, 0.0f) + log1pf(__expf(-fabsf(x)));
}

// Load one MFMA B-fragment (B[k][n], n=lane&15, k=k0+j) from a row-major [K][N] global weight.
__device__ __forceinline__ bf16x8 load_wfrag(const float* __restrict__ W, int ldn, int n,
                                             int k0, bool guard, int nmax) {
    bf16x8 f;
    #pragma unroll
    for (int j = 0; j < 8; ++j) {
        float v = (!guard || n < nmax) ? W[(size_t)(k0 + j) * ldn + n] : 0.0f;
        f[j] = (short)f2bf(v);
    }
    return f;
}

extern "C" __global__ void __launch_bounds__(NTHREADS, 4)
hgsm_fused(const float* __restrict__ x_flat, const float* __restrict__ x_spatial,
           const float* __restrict__ g0w, const float* __restrict__ g0b,
           const float* __restrict__ g0g, const float* __restrict__ g0be,
           const float* __restrict__ g1w, const float* __restrict__ g1b,
           const float* __restrict__ g1g, const float* __restrict__ g1be,
           const float* __restrict__ g2w, const float* __restrict__ g2b,
           const float* __restrict__ g2g, const float* __restrict__ g2be,
           const float* __restrict__ g3w, const float* __restrict__ g3b,
           const float* __restrict__ g3g, const float* __restrict__ g3be,
           const float* __restrict__ sp_w, const float* __restrict__ sp_b,
           const float* __restrict__ in_w, const float* __restrict__ conv_w,
           const float* __restrict__ conv_b, const float* __restrict__ xp_w,
           const float* __restrict__ dt_w, const float* __restrict__ dt_b,
           const float* __restrict__ A_log, const float* __restrict__ Dp,
           const float* __restrict__ out_w, const float* __restrict__ ln_g,
           const float* __restrict__ ln_b, const float* __restrict__ h1_w,
           const float* __restrict__ h1_b, const float* __restrict__ h2_w,
           const float* __restrict__ h2_b, float* __restrict__ out)
{
    extern __shared__ char smraw[];
    const int b   = blockIdx.x;
    const int tid = threadIdx.x;

    unsigned short* xb_bf  = (unsigned short*)(smraw + OFF_XB);
    unsigned short* raw_bf = (unsigned short*)(smraw + OFF_RAW);
    unsigned short* zb_bf  = (unsigned short*)(smraw + OFF_ZB);
    unsigned short* xcb_bf = (unsigned short*)(smraw + OFF_XCB);
    unsigned short* ycb_bf = (unsigned short*)(smraw + OFF_YCB);
    unsigned short* tail_bf= (unsigned short*)(smraw + OFF_TAIL);
    float* dtb  = (float*)(smraw + OFF_DTB);
    float* xdbl = (float*)(smraw + OFF_XDBL);
    float* yob  = (float*)(smraw + OFF_YOB);
    float* dtw  = (float*)(smraw + OFF_DTW);
    float* cvwT = (float*)(smraw + OFF_CVWT);
    float* cvb  = (float*)(smraw + OFF_CVB);
    float* dtbl = (float*)(smraw + OFF_DTBL);
    float* Dl   = (float*)(smraw + OFF_DL);
    float* lng  = (float*)(smraw + OFF_LNG);
    float* lnb  = (float*)(smraw + OFF_LNB);

    const int wv   = tid >> 6;        // wave id 0..7
    const int lane = tid & 63;
    const int l15  = lane & 15;
    const int qd   = lane >> 4;       // quad 0..3

    // ---------------- Phase 0: x = x_spatial @ sp_w + sp_b  (fp32 VALU) ----------------
    {
        float* xsp = (float*)(smraw + OFF_RAW);  // 32 KB staging alias
        const float4* src = (const float4*)(x_spatial + (size_t)b * KSEQ * F_SP);
        float4* dst = (float4*)xsp;
        for (int i = tid; i < KSEQ * F_SP / 4; i += NTHREADS) dst[i] = src[i];
        __syncthreads();

        const int d  = tid & 63;
        const int tg = tid >> 6;   // 8 groups x 32 tokens
        float wsp[F_SP];
        #pragma unroll
        for (int f = 0; f < F_SP; ++f) wsp[f] = sp_w[f * D_SP + d];
        const float bias = sp_b[d];
        #pragma unroll 1
        for (int t = tg * 32; t < tg * 32 + 32; ++t) {
            float acc = bias;
            #pragma unroll
            for (int f4 = 0; f4 < F_SP / 4; ++f4) {
                float4 xv = ((const float4*)xsp)[t * (F_SP / 4) + f4];
                acc += xv.x * wsp[f4*4+0] + xv.y * wsp[f4*4+1]
                     + xv.z * wsp[f4*4+2] + xv.w * wsp[f4*4+3];
            }
            xb_bf[t * 72 + d] = f2bf(acc);
        }
        __syncthreads();
    }

    // scan mapping
    const int d_sc = tid >> 2;        // channel 0..127
    const int shq  = tid & 3;         // state shard (4 states each)
    // LN mapping
    const int t_ln = tid >> 5;        // token 0..15
    const int j_ln = tid & 31;

    // ---------------- Mamba layers ----------------
    #pragma unroll 1
    for (int l = 0; l < NL; ++l) {
        // ---- stage small weights into LDS ----
        dtw[tid] = dt_w[(size_t)l * DT_RANK * D_IN + tid];                 // 512 exactly
        { const int k = tid >> 7, d = tid & 127;                           // transposed [k][d]
          cvwT[tid] = conv_w[(size_t)l * D_IN * 4 + d * 4 + k]; }
        if (tid < D_IN) {
            cvb[tid]  = conv_b[l * D_IN + tid];
            dtbl[tid] = dt_b[l * D_IN + tid];
            Dl[tid]   = Dp[l * D_IN + tid];
        }
        if (tid < D_SP) {
            lng[tid] = ln_g[l * D_SP + tid];
            lnb[tid] = ln_b[l * D_SP + tid];
        }
        if (tid < 3 * D_IN) tail_bf[tid] = 0;

        // ---- per-wave register B-fragments ----
        // in_proj: every wave owns N-tiles {2wv, 2wv+1} of 16 cols, K=64 (2 ksteps)
        bf16x8 binw[4];
        {
            const float* W = in_w + (size_t)l * D_SP * 256;
            const int nt0 = 2 * wv, nt1 = 2 * wv + 1;
            binw[0] = load_wfrag(W, 256, nt0 * 16 + l15, 0  + qd * 8, false, 0);
            binw[1] = load_wfrag(W, 256, nt0 * 16 + l15, 32 + qd * 8, false, 0);
            binw[2] = load_wfrag(W, 256, nt1 * 16 + l15, 0  + qd * 8, false, 0);
            binw[3] = load_wfrag(W, 256, nt1 * 16 + l15, 32 + qd * 8, false, 0);
        }
        // aux fragments: waves 0..3 -> out_proj tile wv (K=128, 4 ksteps)
        //                waves 4..6 -> xp tile wv-4 (K=128, 4 ksteps, N padded to 48)
        bf16x8 baux[4];
        if (wv < 4) {
            const float* W = out_w + (size_t)l * D_IN * D_SP;
            #pragma unroll
            for (int s = 0; s < 4; ++s)
                baux[s] = load_wfrag(W, D_SP, wv * 16 + l15, s * 32 + qd * 8, false, 0);
        } else if (wv < 7) {
            const float* W = xp_w + (size_t)l * D_IN * 36;
            #pragma unroll
            for (int s = 0; s < 4; ++s)
                baux[s] = load_wfrag(W, 36, (wv - 4) * 16 + l15, s * 32 + qd * 8, true, 36);
        }

        float aA[4];
        #pragma unroll
        for (int s = 0; s < 4; ++s)
            aA[s] = -__expf(A_log[(size_t)l * D_IN * D_ST + d_sc * D_ST + shq * 4 + s]);
        float hst[4];
        #pragma unroll
        for (int s = 0; s < 4; ++s) hst[s] = 0.0f;

        __syncthreads();

        #pragma unroll 1
        for (int c = 0; c < NCH; ++c) {
            const int t0 = c * TCH;

            // ---- P1: in_proj MFMA (all 8 waves, 2 tiles each) ----
            {
                const bf16x8 a0 = *(const bf16x8*)(xb_bf + (t0 + l15) * 72 + 0  + qd * 8);
                const bf16x8 a1 = *(const bf16x8*)(xb_bf + (t0 + l15) * 72 + 32 + qd * 8);
                f32x4 acc0 = {0.f, 0.f, 0.f, 0.f};
                f32x4 acc1 = {0.f, 0.f, 0.f, 0.f};
                acc0 = __builtin_amdgcn_mfma_f32_16x16x32_bf16(a0, binw[0], acc0, 0, 0, 0);
                acc0 = __builtin_amdgcn_mfma_f32_16x16x32_bf16(a1, binw[1], acc0, 0, 0, 0);
                acc1 = __builtin_amdgcn_mfma_f32_16x16x32_bf16(a0, binw[2], acc1, 0, 0, 0);
                acc1 = __builtin_amdgcn_mfma_f32_16x16x32_bf16(a1, binw[3], acc1, 0, 0, 0);
                const int nt0 = 2 * wv, nt1 = 2 * wv + 1;
                #pragma unroll
                for (int r = 0; r < 4; ++r) {
                    const int m = qd * 4 + r;
                    if (nt0 < 8) raw_bf[m * 136 + nt0 * 16 + l15] = f2bf(acc0[r]);
                    else         zb_bf [m * 136 + (nt0 - 8) * 16 + l15] = f2bf(acc0[r]);
                    if (nt1 < 8) raw_bf[m * 136 + nt1 * 16 + l15] = f2bf(acc1[r]);
                    else         zb_bf [m * 136 + (nt1 - 8) * 16 + l15] = f2bf(acc1[r]);
                }
            }
            __syncthreads();  // B1

            // ---- P2: causal depthwise conv (k=4) + bias + silu ----
            for (int idx = tid; idx < TCH * D_IN; idx += NTHREADS) {
                const int t = idx >> 7, d = idx & 127;
                float s = cvb[d];
                #pragma unroll
                for (int k = 0; k < 4; ++k) {
                    const int tt = t - 3 + k;
                    const float v = bf2f((tt >= 0) ? raw_bf[tt * 136 + d]
                                                   : tail_bf[(tt + 3) * 128 + d]);
                    s += cvwT[k * 128 + d] * v;
                }
                xcb_bf[t * 136 + d] = f2bf(siluf(s));
            }
            __syncthreads();  // B2

            // ---- P3: xp MFMA (waves 4..6, one 16-col tile each, K=128) ----
            if (wv >= 4 && wv < 7) {
                f32x4 acc = {0.f, 0.f, 0.f, 0.f};
                #pragma unroll
                for (int s = 0; s < 4; ++s) {
                    const bf16x8 a = *(const bf16x8*)(xcb_bf + l15 * 136 + s * 32 + qd * 8);
                    acc = __builtin_amdgcn_mfma_f32_16x16x32_bf16(a, baux[s], acc, 0, 0, 0);
                }
                const int nt = wv - 4;
                #pragma unroll
                for (int r = 0; r < 4; ++r)
                    xdbl[(qd * 4 + r) * 48 + nt * 16 + l15] = acc[r];
            }
            __syncthreads();  // B3

            // ---- P4: dt = softplus(xdbl[:,:4]@dt_w + dt_b)  +  save conv tail ----
            if (tid < 3 * D_IN)
                tail_bf[tid] = raw_bf[(13 + (tid >> 7)) * 136 + (tid & 127)];
            for (int idx = tid; idx < TCH * D_IN; idx += NTHREADS) {
                const int t = idx >> 7, d = idx & 127;
                float v = dtbl[d];
                #pragma unroll
                for (int r = 0; r < DT_RANK; ++r)
                    v += xdbl[t * 48 + r] * dtw[r * D_IN + d];
                dtb[idx] = softplusf(v);
            }
            __syncthreads();  // B4

            // ---- P5: selective scan + gate (fused) ----
            #pragma unroll
            for (int t = 0; t < TCH; ++t) {
                const float dtv = dtb[t * D_IN + d_sc];
                const float xv  = bf2f(xcb_bf[t * 136 + d_sc]);
                const float dx  = dtv * xv;
                float yp = 0.0f;
                #pragma unroll
                for (int s = 0; s < 4; ++s) {
                    const float Bv = xdbl[t * 48 + DT_RANK + shq * 4 + s];
                    const float Cv = xdbl[t * 48 + DT_RANK + D_ST + shq * 4 + s];
                    const float dA = __expf(dtv * aA[s]);
                    hst[s] = dA * hst[s] + dx * Bv;
                    yp += hst[s] * Cv;
                }
                yp += __shfl_xor(yp, 1, 64);
                yp += __shfl_xor(yp, 2, 64);
                if (shq == 0) {
                    const float yv = yp + xv * Dl[d_sc];
                    const float zv = bf2f(zb_bf[t * 136 + d_sc]);
                    ycb_bf[t * 136 + d_sc] = f2bf(yv * siluf(zv));
                }
            }
            __syncthreads();  // B5

            // ---- P6: out_proj MFMA (waves 0..3, one 16-col tile each, K=128) ----
            if (wv < 4) {
                f32x4 acc = {0.f, 0.f, 0.f, 0.f};
                #pragma unroll
                for (int s = 0; s < 4; ++s) {
                    const bf16x8 a = *(const bf16x8*)(ycb_bf + l15 * 136 + s * 32 + qd * 8);
                    acc = __builtin_amdgcn_mfma_f32_16x16x32_bf16(a, baux[s], acc, 0, 0, 0);
                }
                #pragma unroll
                for (int r = 0; r < 4; ++r)
                    yob[(qd * 4 + r) * 65 + wv * 16 + l15] = acc[r];
            }
            __syncthreads();  // B6

            // ---- P7: LN (butterfly stats) + residual into xb ----
            {
                const float s1 = yob[t_ln * 65 + j_ln];
                const float s2 = yob[t_ln * 65 + j_ln + 32];
                float sum = s1 + s2;
                float ssq = s1 * s1 + s2 * s2;
                #pragma unroll
                for (int m = 1; m <= 16; m <<= 1) {
                    sum += __shfl_xor(sum, m, 64);
                    ssq += __shfl_xor(ssq, m, 64);
                }
                const float mu  = sum * (1.0f / D_SP);
                const float var = ssq * (1.0f / D_SP) - mu * mu;
                const float rs  = rsqrtf(var + 1e-5f);
                const int base = (t0 + t_ln) * 72;
                const float o1 = bf2f(xb_bf[base + j_ln]) +
                                 (s1 - mu) * rs * lng[j_ln] + lnb[j_ln];
                const float o2 = bf2f(xb_bf[base + j_ln + 32]) +
                                 (s2 - mu) * rs * lng[j_ln + 32] + lnb[j_ln + 32];
                xb_bf[base + j_ln]      = f2bf(o1);
                xb_bf[base + j_ln + 32] = f2bf(o2);
            }
            __syncthreads();  // B7 (end of chunk)
        }
    }

    // ---------------- Head (scratch aliases dtb region) ----------------
    float* hsc   = (float*)(smraw + OFF_DTB);
    float* psum  = hsc;        // 8*64
    float* comb  = hsc + 512;  // 192
    float* gh    = hsc + 704;  // 128
    float* hb1   = hsc + 832;  // 64
    float* gstat = hsc + 896;  // 8

    {
        const int d = tid & 63, grp = tid >> 6;
        float s = 0.0f;
        #pragma unroll 4
        for (int t = grp * 32; t < grp * 32 + 32; ++t) s += bf2f(xb_bf[t * 72 + d]);
        psum[grp * 64 + d] = s;
    }
    if (tid >= 64 && tid < 192) {
        const int g = (tid - 64) >> 5, cc = (tid - 64) & 31;
        const float* gw; const float* gb; int dd, so;
        if      (g == 0) { gw = g0w; gb = g0b; dd = 4; so = 0;  }
        else if (g == 1) { gw = g1w; gb = g1b; dd = 3; so = 4;  }
        else if (g == 2) { gw = g2w; gb = g2b; dd = 4; so = 7;  }
        else             { gw = g3w; gb = g3b; dd = 3; so = 11; }
        float acc = gb[cc];
        for (int f = 0; f < dd; ++f)
            acc += x_flat[(size_t)b * F_FLAT + so + f] * gw[f * GD + cc];
        gh[tid - 64] = fmaxf(acc, 0.0f);
    }
    __syncthreads();

    if (tid < D_SP) {
        float s = 0.0f;
        #pragma unroll
        for (int g = 0; g < 8; ++g) s += psum[g * 64 + tid];
        comb[4 * GD + tid] = s * (1.0f / KSEQ);
    } else if (tid >= NTHREADS - 4) {
        const int g = tid - (NTHREADS - 4);
        float mu = 0.0f;
        #pragma unroll
        for (int cc = 0; cc < GD; ++cc) mu += gh[g * GD + cc];
        mu *= (1.0f / GD);
        float var = 0.0f;
        #pragma unroll
        for (int cc = 0; cc < GD; ++cc) {
            const float dd = gh[g * GD + cc] - mu;
            var += dd * dd;
        }
        var *= (1.0f / GD);
        gstat[g] = mu;
        gstat[4 + g] = rsqrtf(var + 1e-5f);
    }
    __syncthreads();

    if (tid < 128) {
        const int g = tid >> 5, cc = tid & 31;
        const float* gg; const float* gbe;
        if      (g == 0) { gg = g0g; gbe = g0be; }
        else if (g == 1) { gg = g1g; gbe = g1be; }
        else if (g == 2) { gg = g2g; gbe = g2be; }
        else             { gg = g3g; gbe = g3be; }
        comb[tid] = (gh[tid] - gstat[g]) * gstat[4 + g] * gg[cc] + gbe[cc];
    }
    __syncthreads();

    if (tid < DM) {
        float acc = h1_b[tid];
        #pragma unroll 4
        for (int k = 0; k < 4 * GD + D_SP; ++k) acc += comb[k] * h1_w[k * DM + tid];
        hb1[tid] = fmaxf(acc, 0.0f);
    }
    __syncthreads();

    if (tid == 0) {
        float acc = h2_b[0];
        #pragma unroll
        for (int j = 0; j < DM; ++j) acc += hb1[j] * h2_w[j];
        out[b] = 1.0f / (1.0f + __expf(-acc));
    }
}

extern "C" void kernel_launch(void* const* d_in, const int* in_sizes, int n_in,
                              void* d_out, int out_size, void* d_ws, size_t ws_size,
                              hipStream_t stream) {
    (void)n_in; (void)d_ws; (void)ws_size; (void)out_size;
    const float* x_flat    = (const float*)d_in[0];
    const float* x_spatial = (const float*)d_in[1];
    const float* g0w = (const float*)d_in[2];
    const float* g0b = (const float*)d_in[3];
    const float* g0g = (const float*)d_in[4];
    const float* g0be = (const float*)d_in[5];
    const float* g1w = (const float*)d_in[6];
    const float* g1b = (const float*)d_in[7];
    const float* g1g = (const float*)d_in[8];
    const float* g1be = (const float*)d_in[9];
    const float* g2w = (const float*)d_in[10];
    const float* g2b = (const float*)d_in[11];
    const float* g2g = (const float*)d_in[12];
    const float* g2be = (const float*)d_in[13];
    const float* g3w = (const float*)d_in[14];
    const float* g3b = (const float*)d_in[15];
    const float* g3g = (const float*)d_in[16];
    const float* g3be = (const float*)d_in[17];
    const float* sp_w = (const float*)d_in[18];
    const float* sp_b = (const float*)d_in[19];
    const float* in_w = (const float*)d_in[20];
    const float* conv_w = (const float*)d_in[21];
    const float* conv_b = (const float*)d_in[22];
    const float* xp_w = (const float*)d_in[23];
    const float* dt_w = (const float*)d_in[24];
    const float* dt_b = (const float*)d_in[25];
    const float* A_log = (const float*)d_in[26];
    const float* Dp = (const float*)d_in[27];
    const float* out_w = (const float*)d_in[28];
    const float* ln_g = (const float*)d_in[29];
    const float* ln_b = (const float*)d_in[30];
    const float* h1_w = (const float*)d_in[31];
    const float* h1_b = (const float*)d_in[32];
    const float* h2_w = (const float*)d_in[33];
    const float* h2_b = (const float*)d_in[34];
    float* out = (float*)d_out;

    const int B = in_sizes[0] / F_FLAT;
    (void)hipFuncSetAttribute((const void*)hgsm_fused,
                              hipFuncAttributeMaxDynamicSharedMemorySize, SM_BYTES);

    hipLaunchKernelGGL(hgsm_fused, dim3(B), dim3(NTHREADS), SM_BYTES, stream,
                       x_flat, x_spatial,
                       g0w, g0b, g0g, g0be, g1w, g1b, g1g, g1be,
                       g2w, g2b, g2g, g2be, g3w, g3b, g3g, g3be,
                       sp_w, sp_b, in_w, conv_w, conv_b, xp_w, dt_w, dt_b,
                       A_log, Dp, out_w, ln_g, ln_b, h1_w, h1_b, h2_w, h2_b,
                       out);
}

// Round 4
// 766.445 us; speedup vs baseline: 4.9342x; 1.3801x over previous
//
#include <hip/hip_runtime.h>
#include <math.h>

#define KSEQ    256
#define F_SP    32
#define F_FLAT  14
#define D_SP    64
#define D_IN    128
#define D_ST    16
#define DT_RANK 4
#define GD      32
#define DM      64
#define NL      2
#define TCH     16
#define NCH     (KSEQ / TCH)
#define NTHREADS 512

// ---- LDS layout (BYTE offsets, 16B-aligned) ----
#define OFF_XB    0        // ushort 256*72 = 36864   persistent x (bf16)
#define OFF_RAW   36864    // float  16*132 = 8448    xz pre-conv (fp32)
#define OFF_ZB    45312    // ushort 16*136 = 4352    z gate (bf16)
#define OFF_XCB   49664    // ushort 16*136 = 4352    conv+silu out (bf16)
#define OFF_YCB0  54016    // ushort 16*136 = 4352    gated scan out, buf 0
#define OFF_YCB1  58368    // ushort 16*136 = 4352    gated scan out, buf 1
#define OFF_DTB   62720    // float  16*128 = 8192    dt (fp32)  [head scratch aliases]
#define OFF_XDBL  70912    // float  16*48  = 3072    xp out (fp32)
#define OFF_YOB   73984    // float  16*65  = 4160    out_proj out (fp32)
#define OFF_TAIL0 78144    // float  3*128  = 1536    conv tail, buf 0
#define OFF_TAIL1 79680    // float  3*128  = 1536    conv tail, buf 1
#define SM_BYTES  81216    // 79.3 KiB -> 2 blocks/CU
// phase0 staging (32 KB fp32) aliases OFF_RAW..OFF_DTB end (33.. KB available)

typedef __attribute__((ext_vector_type(8))) short bf16x8;
typedef __attribute__((ext_vector_type(4))) float f32x4;

__device__ __forceinline__ unsigned short f2bf(float f) {
    union { float f; unsigned int u; } v; v.f = f;
    unsigned int r = v.u + 0x7FFFu + ((v.u >> 16) & 1u);   // RNE
    return (unsigned short)(r >> 16);
}
__device__ __forceinline__ float bf2f(unsigned short h) {
    union { unsigned int u; float f; } v; v.u = ((unsigned int)h) << 16; return v.f;
}
__device__ __forceinline__ float sigf(float x) {
    return __builtin_amdgcn_rcpf(1.0f + __expf(-x));       // fast rcp, no fp32 div
}
__device__ __forceinline__ float siluf(float x) { return x * sigf(x); }
__device__ __forceinline__ float softplusf(float x) {
    return fmaxf(x, 0.0f) + __logf(1.0f + __expf(-fabsf(x)));
}

// MFMA B-fragment (B[k][n], n=lane&15, k=k0+j) from row-major [K][N] fp32 weight.
__device__ __forceinline__ bf16x8 load_wfrag(const float* __restrict__ W, int ldn, int n,
                                             int k0, bool guard, int nmax) {
    bf16x8 f;
    #pragma unroll
    for (int j = 0; j < 8; ++j) {
        float v = (!guard || n < nmax) ? W[(size_t)(k0 + j) * ldn + n] : 0.0f;
        f[j] = (short)f2bf(v);
    }
    return f;
}

extern "C" __global__ void __launch_bounds__(NTHREADS, 4)
hgsm_fused(const float* __restrict__ x_flat, const float* __restrict__ x_spatial,
           const float* __restrict__ g0w, const float* __restrict__ g0b,
           const float* __restrict__ g0g, const float* __restrict__ g0be,
           const float* __restrict__ g1w, const float* __restrict__ g1b,
           const float* __restrict__ g1g, const float* __restrict__ g1be,
           const float* __restrict__ g2w, const float* __restrict__ g2b,
           const float* __restrict__ g2g, const float* __restrict__ g2be,
           const float* __restrict__ g3w, const float* __restrict__ g3b,
           const float* __restrict__ g3g, const float* __restrict__ g3be,
           const float* __restrict__ sp_w, const float* __restrict__ sp_b,
           const float* __restrict__ in_w, const float* __restrict__ conv_w,
           const float* __restrict__ conv_b, const float* __restrict__ xp_w,
           const float* __restrict__ dt_w, const float* __restrict__ dt_b,
           const float* __restrict__ A_log, const float* __restrict__ Dp,
           const float* __restrict__ out_w, const float* __restrict__ ln_g,
           const float* __restrict__ ln_b, const float* __restrict__ h1_w,
           const float* __restrict__ h1_b, const float* __restrict__ h2_w,
           const float* __restrict__ h2_b, float* __restrict__ out)
{
    extern __shared__ char smraw[];
    const int b   = blockIdx.x;
    const int tid = threadIdx.x;

    unsigned short* xb_bf  = (unsigned short*)(smraw + OFF_XB);
    float*          raw_f  = (float*)(smraw + OFF_RAW);
    unsigned short* zb_bf  = (unsigned short*)(smraw + OFF_ZB);
    unsigned short* xcb_bf = (unsigned short*)(smraw + OFF_XCB);
    unsigned short* ycb0   = (unsigned short*)(smraw + OFF_YCB0);
    unsigned short* ycb1   = (unsigned short*)(smraw + OFF_YCB1);
    float* dtb   = (float*)(smraw + OFF_DTB);
    float* xdbl  = (float*)(smraw + OFF_XDBL);
    float* yob   = (float*)(smraw + OFF_YOB);
    float* tail0 = (float*)(smraw + OFF_TAIL0);
    float* tail1 = (float*)(smraw + OFF_TAIL1);

    const int wv   = tid >> 6;        // wave 0..7
    const int lane = tid & 63;
    const int l15  = lane & 15;
    const int qd   = lane >> 4;       // quad 0..3
    const int dcv  = tid & 127;       // conv/dt channel
    const int tq   = tid >> 7;        // conv/dt token-quad 0..3
    const int d_sc = tid >> 2;        // scan channel
    const int shq  = tid & 3;         // scan state shard
    const int t_ln = tid >> 5;        // LN token
    const int j_ln = tid & 31;        // LN column pair

    // ---------------- Phase 0: x = x_spatial @ sp_w + sp_b ----------------
    {
        float* xsp = (float*)(smraw + OFF_RAW);  // 32 KB staging alias
        const float4* src = (const float4*)(x_spatial + (size_t)b * KSEQ * F_SP);
        float4* dst = (float4*)xsp;
        for (int i = tid; i < KSEQ * F_SP / 4; i += NTHREADS) dst[i] = src[i];
        __syncthreads();

        const int d  = tid & 63;
        const int tg = tid >> 6;
        float wsp[F_SP];
        #pragma unroll
        for (int f = 0; f < F_SP; ++f) wsp[f] = sp_w[f * D_SP + d];
        const float bias = sp_b[d];
        #pragma unroll 1
        for (int t = tg * 32; t < tg * 32 + 32; ++t) {
            float acc = bias;
            #pragma unroll
            for (int f4 = 0; f4 < F_SP / 4; ++f4) {
                float4 xv = ((const float4*)xsp)[t * (F_SP / 4) + f4];
                acc += xv.x * wsp[f4*4+0] + xv.y * wsp[f4*4+1]
                     + xv.z * wsp[f4*4+2] + xv.w * wsp[f4*4+3];
            }
            xb_bf[t * 72 + d] = f2bf(acc);
        }
        __syncthreads();
    }

    // ---------------- Mamba layers ----------------
    #pragma unroll 1
    for (int l = 0; l < NL; ++l) {
        // ---- per-thread register weights (all indices tid-invariant) ----
        bf16x8 binw[4];
        {
            const float* W = in_w + (size_t)l * D_SP * 256;
            const int nt0 = 2 * wv, nt1 = 2 * wv + 1;
            binw[0] = load_wfrag(W, 256, nt0 * 16 + l15, 0  + qd * 8, false, 0);
            binw[1] = load_wfrag(W, 256, nt0 * 16 + l15, 32 + qd * 8, false, 0);
            binw[2] = load_wfrag(W, 256, nt1 * 16 + l15, 0  + qd * 8, false, 0);
            binw[3] = load_wfrag(W, 256, nt1 * 16 + l15, 32 + qd * 8, false, 0);
        }
        bf16x8 baux[4];
        if (wv < 4) {
            const float* W = out_w + (size_t)l * D_IN * D_SP;
            #pragma unroll
            for (int s = 0; s < 4; ++s)
                baux[s] = load_wfrag(W, D_SP, wv * 16 + l15, s * 32 + qd * 8, false, 0);
        } else if (wv < 7) {
            const float* W = xp_w + (size_t)l * D_IN * 36;
            #pragma unroll
            for (int s = 0; s < 4; ++s)
                baux[s] = load_wfrag(W, 36, (wv - 4) * 16 + l15, s * 32 + qd * 8, true, 36);
        }
        const float4 cvwr = *(const float4*)(conv_w + (size_t)l * D_IN * 4 + dcv * 4);
        const float  cvbv = conv_b[l * D_IN + dcv];
        float dtwr[4];
        #pragma unroll
        for (int r = 0; r < 4; ++r) dtwr[r] = dt_w[(size_t)l * DT_RANK * D_IN + r * D_IN + dcv];
        const float dtbv = dt_b[l * D_IN + dcv];
        const float Dlv  = Dp[l * D_IN + d_sc];
        float aA[4];
        {
            const float4 al = *(const float4*)(A_log + (size_t)l * D_IN * D_ST + d_sc * D_ST + shq * 4);
            aA[0] = -__expf(al.x); aA[1] = -__expf(al.y);
            aA[2] = -__expf(al.z); aA[3] = -__expf(al.w);
        }
        const float lngv0 = ln_g[l * D_SP + j_ln], lngv1 = ln_g[l * D_SP + j_ln + 32];
        const float lnbv0 = ln_b[l * D_SP + j_ln], lnbv1 = ln_b[l * D_SP + j_ln + 32];
        float hst[4];
        #pragma unroll
        for (int s = 0; s < 4; ++s) hst[s] = 0.0f;

        if (tid < 3 * D_IN) tail0[tid] = 0.0f;
        __syncthreads();

        #pragma unroll 1
        for (int c = 0; c < NCH; ++c) {
            const int t0 = c * TCH;
            const int p  = c & 1;
            float* tailp = p ? tail1 : tail0;
            float* tailn = p ? tail0 : tail1;
            unsigned short* ycb_w = p ? ycb1 : ycb0;   // scan writes (chunk c)
            unsigned short* ycb_r = p ? ycb0 : ycb1;   // out_proj reads (chunk c-1)

            // ---- A: in_proj MFMA (all 8 waves, 2 N-tiles each) ----
            {
                const bf16x8 a0 = *(const bf16x8*)(xb_bf + (t0 + l15) * 72 + qd * 8);
                const bf16x8 a1 = *(const bf16x8*)(xb_bf + (t0 + l15) * 72 + 32 + qd * 8);
                f32x4 acc0 = {0.f, 0.f, 0.f, 0.f};
                f32x4 acc1 = {0.f, 0.f, 0.f, 0.f};
                acc0 = __builtin_amdgcn_mfma_f32_16x16x32_bf16(a0, binw[0], acc0, 0, 0, 0);
                acc0 = __builtin_amdgcn_mfma_f32_16x16x32_bf16(a1, binw[1], acc0, 0, 0, 0);
                acc1 = __builtin_amdgcn_mfma_f32_16x16x32_bf16(a0, binw[2], acc1, 0, 0, 0);
                acc1 = __builtin_amdgcn_mfma_f32_16x16x32_bf16(a1, binw[3], acc1, 0, 0, 0);
                if (wv < 4) {                         // cols 0..127 -> raw (fp32)
                    const int n0 = 2 * wv * 16 + l15;
                    #pragma unroll
                    for (int r = 0; r < 4; ++r) {
                        const int m = qd * 4 + r;
                        raw_f[m * 132 + n0]      = acc0[r];
                        raw_f[m * 132 + n0 + 16] = acc1[r];
                    }
                } else {                              // cols 128..255 -> z (bf16)
                    const int n0 = (2 * wv - 8) * 16 + l15;
                    #pragma unroll
                    for (int r = 0; r < 4; ++r) {
                        const int m = qd * 4 + r;
                        zb_bf[m * 136 + n0]      = f2bf(acc0[r]);
                        zb_bf[m * 136 + n0 + 16] = f2bf(acc1[r]);
                    }
                }
            }
            __syncthreads();  // A->B

            // ---- B: causal depthwise conv + bias + silu (4 consecutive tokens/thread) ----
            {
                float rr[7];
                #pragma unroll
                for (int i = 0; i < 7; ++i) {
                    const int t = tq * 4 - 3 + i;
                    rr[i] = (t >= 0) ? raw_f[t * 132 + dcv] : tailp[(t + 3) * 128 + dcv];
                }
                #pragma unroll
                for (int o = 0; o < 4; ++o) {
                    float s = cvbv + cvwr.x * rr[o] + cvwr.y * rr[o+1]
                                   + cvwr.z * rr[o+2] + cvwr.w * rr[o+3];
                    xcb_bf[(tq * 4 + o) * 136 + dcv] = f2bf(siluf(s));
                }
                if (tq == 3) {
                    tailn[0 * 128 + dcv] = rr[4];
                    tailn[1 * 128 + dcv] = rr[5];
                    tailn[2 * 128 + dcv] = rr[6];
                }
            }
            __syncthreads();  // B->C

            // ---- C: xp(c) on waves 4..6  ||  out_proj(c-1) on waves 0..3 ----
            if (wv < 4) {
                if (c > 0) {
                    f32x4 acc = {0.f, 0.f, 0.f, 0.f};
                    #pragma unroll
                    for (int s = 0; s < 4; ++s) {
                        const bf16x8 a = *(const bf16x8*)(ycb_r + l15 * 136 + s * 32 + qd * 8);
                        acc = __builtin_amdgcn_mfma_f32_16x16x32_bf16(a, baux[s], acc, 0, 0, 0);
                    }
                    #pragma unroll
                    for (int r = 0; r < 4; ++r)
                        yob[(qd * 4 + r) * 65 + wv * 16 + l15] = acc[r];
                }
            } else if (wv < 7) {
                f32x4 acc = {0.f, 0.f, 0.f, 0.f};
                #pragma unroll
                for (int s = 0; s < 4; ++s) {
                    const bf16x8 a = *(const bf16x8*)(xcb_bf + l15 * 136 + s * 32 + qd * 8);
                    acc = __builtin_amdgcn_mfma_f32_16x16x32_bf16(a, baux[s], acc, 0, 0, 0);
                }
                const int nt = wv - 4;
                #pragma unroll
                for (int r = 0; r < 4; ++r)
                    xdbl[(qd * 4 + r) * 48 + nt * 16 + l15] = acc[r];
            }
            __syncthreads();  // C->D

            // ---- D: dt(c) (all threads)  +  LN(c-1)+residual ----
            {
                #pragma unroll
                for (int o = 0; o < 4; ++o) {
                    const int t = tq * 4 + o;
                    const f32x4 xr = *(const f32x4*)(xdbl + t * 48);
                    const float v = dtbv + xr[0]*dtwr[0] + xr[1]*dtwr[1]
                                         + xr[2]*dtwr[2] + xr[3]*dtwr[3];
                    dtb[t * 128 + dcv] = softplusf(v);
                }
            }
            if (c > 0) {
                const int pt0 = t0 - TCH;
                const float s1 = yob[t_ln * 65 + j_ln];
                const float s2 = yob[t_ln * 65 + j_ln + 32];
                float sum = s1 + s2;
                float ssq = s1 * s1 + s2 * s2;
                #pragma unroll
                for (int m = 1; m <= 16; m <<= 1) {
                    sum += __shfl_xor(sum, m, 64);
                    ssq += __shfl_xor(ssq, m, 64);
                }
                const float mu  = sum * (1.0f / D_SP);
                const float var = ssq * (1.0f / D_SP) - mu * mu;
                const float rs  = rsqrtf(var + 1e-5f);
                const int base = (pt0 + t_ln) * 72;
                xb_bf[base + j_ln]      = f2bf(bf2f(xb_bf[base + j_ln])
                                               + (s1 - mu) * rs * lngv0 + lnbv0);
                xb_bf[base + j_ln + 32] = f2bf(bf2f(xb_bf[base + j_ln + 32])
                                               + (s2 - mu) * rs * lngv1 + lnbv1);
            }
            __syncthreads();  // D->E

            // ---- E: selective scan + gate -> ycb_w ----
            #pragma unroll
            for (int t = 0; t < TCH; ++t) {
                const float dtv = dtb[t * 128 + d_sc];
                const float xv  = bf2f(xcb_bf[t * 136 + d_sc]);
                const float dx  = dtv * xv;
                const f32x4 Bv = *(const f32x4*)(xdbl + t * 48 + DT_RANK + shq * 4);
                const f32x4 Cv = *(const f32x4*)(xdbl + t * 48 + DT_RANK + D_ST + shq * 4);
                float yp = 0.0f;
                #pragma unroll
                for (int s = 0; s < 4; ++s) {
                    const float dA = __expf(dtv * aA[s]);
                    hst[s] = dA * hst[s] + dx * Bv[s];
                    yp += hst[s] * Cv[s];
                }
                yp += __shfl_xor(yp, 1, 64);
                yp += __shfl_xor(yp, 2, 64);
                if (shq == 0) {
                    const float yv = yp + xv * Dlv;
                    const float zv = bf2f(zb_bf[t * 136 + d_sc]);
                    ycb_w[t * 136 + d_sc] = f2bf(yv * siluf(zv));
                }
            }
            __syncthreads();  // E -> next A
        }

        // ---- layer epilogue: out_proj + LN for the last chunk ----
        if (wv < 4) {
            unsigned short* ycb_r = ((NCH - 1) & 1) ? ycb1 : ycb0;
            f32x4 acc = {0.f, 0.f, 0.f, 0.f};
            #pragma unroll
            for (int s = 0; s < 4; ++s) {
                const bf16x8 a = *(const bf16x8*)(ycb_r + l15 * 136 + s * 32 + qd * 8);
                acc = __builtin_amdgcn_mfma_f32_16x16x32_bf16(a, baux[s], acc, 0, 0, 0);
            }
            #pragma unroll
            for (int r = 0; r < 4; ++r)
                yob[(qd * 4 + r) * 65 + wv * 16 + l15] = acc[r];
        }
        __syncthreads();
        {
            const int pt0 = (NCH - 1) * TCH;
            const float s1 = yob[t_ln * 65 + j_ln];
            const float s2 = yob[t_ln * 65 + j_ln + 32];
            float sum = s1 + s2;
            float ssq = s1 * s1 + s2 * s2;
            #pragma unroll
            for (int m = 1; m <= 16; m <<= 1) {
                sum += __shfl_xor(sum, m, 64);
                ssq += __shfl_xor(ssq, m, 64);
            }
            const float mu  = sum * (1.0f / D_SP);
            const float var = ssq * (1.0f / D_SP) - mu * mu;
            const float rs  = rsqrtf(var + 1e-5f);
            const int base = (pt0 + t_ln) * 72;
            xb_bf[base + j_ln]      = f2bf(bf2f(xb_bf[base + j_ln])
                                           + (s1 - mu) * rs * lngv0 + lnbv0);
            xb_bf[base + j_ln + 32] = f2bf(bf2f(xb_bf[base + j_ln + 32])
                                           + (s2 - mu) * rs * lngv1 + lnbv1);
        }
        __syncthreads();
    }

    // ---------------- Head (scratch aliases dtb region) ----------------
    float* hsc   = (float*)(smraw + OFF_DTB);
    float* psum  = hsc;        // 8*64
    float* comb  = hsc + 512;  // 192
    float* gh    = hsc + 704;  // 128
    float* hb1   = hsc + 832;  // 64
    float* gstat = hsc + 896;  // 8

    {
        const int d = tid & 63, grp = tid >> 6;
        float s = 0.0f;
        #pragma unroll 4
        for (int t = grp * 32; t < grp * 32 + 32; ++t) s += bf2f(xb_bf[t * 72 + d]);
        psum[grp * 64 + d] = s;
    }
    if (tid >= 64 && tid < 192) {
        const int g = (tid - 64) >> 5, cc = (tid - 64) & 31;
        const float* gw; const float* gb; int dd, so;
        if      (g == 0) { gw = g0w; gb = g0b; dd = 4; so = 0;  }
        else if (g == 1) { gw = g1w; gb = g1b; dd = 3; so = 4;  }
        else if (g == 2) { gw = g2w; gb = g2b; dd = 4; so = 7;  }
        else             { gw = g3w; gb = g3b; dd = 3; so = 11; }
        float acc = gb[cc];
        for (int f = 0; f < dd; ++f)
            acc += x_flat[(size_t)b * F_FLAT + so + f] * gw[f * GD + cc];
        gh[tid - 64] = fmaxf(acc, 0.0f);
    }
    __syncthreads();

    if (tid < D_SP) {
        float s = 0.0f;
        #pragma unroll
        for (int g = 0; g < 8; ++g) s += psum[g * 64 + tid];
        comb[4 * GD + tid] = s * (1.0f / KSEQ);
    } else if (tid >= NTHREADS - 4) {
        const int g = tid - (NTHREADS - 4);
        float mu = 0.0f;
        #pragma unroll
        for (int cc = 0; cc < GD; ++cc) mu += gh[g * GD + cc];
        mu *= (1.0f / GD);
        float var = 0.0f;
        #pragma unroll
        for (int cc = 0; cc < GD; ++cc) {
            const float dd = gh[g * GD + cc] - mu;
            var += dd * dd;
        }
        var *= (1.0f / GD);
        gstat[g] = mu;
        gstat[4 + g] = rsqrtf(var + 1e-5f);
    }
    __syncthreads();

    if (tid < 128) {
        const int g = tid >> 5, cc = tid & 31;
        const float* gg; const float* gbe;
        if      (g == 0) { gg = g0g; gbe = g0be; }
        else if (g == 1) { gg = g1g; gbe = g1be; }
        else if (g == 2) { gg = g2g; gbe = g2be; }
        else             { gg = g3g; gbe = g3be; }
        comb[tid] = (gh[tid] - gstat[g]) * gstat[4 + g] * gg[cc] + gbe[cc];
    }
    __syncthreads();

    if (tid < DM) {
        float acc = h1_b[tid];
        #pragma unroll 4
        for (int k = 0; k < 4 * GD + D_SP; ++k) acc += comb[k] * h1_w[k * DM + tid];
        hb1[tid] = fmaxf(acc, 0.0f);
    }
    __syncthreads();

    if (tid == 0) {
        float acc = h2_b[0];
        #pragma unroll
        for (int j = 0; j < DM; ++j) acc += hb1[j] * h2_w[j];
        out[b] = sigf(acc);
    }
}

extern "C" void kernel_launch(void* const* d_in, const int* in_sizes, int n_in,
                              void* d_out, int out_size, void* d_ws, size_t ws_size,
                              hipStream_t stream) {
    (void)n_in; (void)d_ws; (void)ws_size; (void)out_size;
    const float* x_flat    = (const float*)d_in[0];
    const float* x_spatial = (const float*)d_in[1];
    const float* g0w = (const float*)d_in[2];
    const float* g0b = (const float*)d_in[3];
    const float* g0g = (const float*)d_in[4];
    const float* g0be = (const float*)d_in[5];
    const float* g1w = (const float*)d_in[6];
    const float* g1b = (const float*)d_in[7];
    const float* g1g = (const float*)d_in[8];
    const float* g1be = (const float*)d_in[9];
    const float* g2w = (const float*)d_in[10];
    const float* g2b = (const float*)d_in[11];
    const float* g2g = (const float*)d_in[12];
    const float* g2be = (const float*)d_in[13];
    const float* g3w = (const float*)d_in[14];
    const float* g3b = (const float*)d_in[15];
    const float* g3g = (const float*)d_in[16];
    const float* g3be = (const float*)d_in[17];
    const float* sp_w = (const float*)d_in[18];
    const float* sp_b = (const float*)d_in[19];
    const float* in_w = (const float*)d_in[20];
    const float* conv_w = (const float*)d_in[21];
    const float* conv_b = (const float*)d_in[22];
    const float* xp_w = (const float*)d_in[23];
    const float* dt_w = (const float*)d_in[24];
    const float* dt_b = (const float*)d_in[25];
    const float* A_log = (const float*)d_in[26];
    const float* Dp = (const float*)d_in[27];
    const float* out_w = (const float*)d_in[28];
    const float* ln_g = (const float*)d_in[29];
    const float* ln_b = (const float*)d_in[30];
    const float* h1_w = (const float*)d_in[31];
    const float* h1_b = (const float*)d_in[32];
    const float* h2_w = (const float*)d_in[33];
    const float* h2_b = (const float*)d_in[34];
    float* out = (float*)d_out;

    const int B = in_sizes[0] / F_FLAT;
    (void)hipFuncSetAttribute((const void*)hgsm_fused,
                              hipFuncAttributeMaxDynamicSharedMemorySize, SM_BYTES);

    hipLaunchKernelGGL(hgsm_fused, dim3(B), dim3(NTHREADS), SM_BYTES, stream,
                       x_flat, x_spatial,
                       g0w, g0b, g0g, g0be, g1w, g1b, g1g, g1be,
                       g2w, g2b, g2g, g2be, g3w, g3b, g3g, g3be,
                       sp_w, sp_b, in_w, conv_w, conv_b, xp_w, dt_w, dt_b,
                       A_log, Dp, out_w, ln_g, ln_b, h1_w, h1_b, h2_w, h2_b,
                       out);
}